// Round 14
// baseline (151.478 us; speedup 1.0000x reference)
//
#include <hip/hip_runtime.h>
#include <cmath>

#define TT 1024
#define BB 8
#define IND 512
#define NCH 32
#define CHL 32          // TT / NCH
#define EPSV 1e-8
#define OUTHALF ((size_t)TT * BB * 4096)

// ---------------- K1: projections — lane=row, wave-uniform W via SMEM ----------
// Each wave: 64 rows (one per lane) x 12 cols (4 per matrix, wave-uniform).
// W reads are uniform -> scalar-pipe s_load (no LDS, no VALU). x staged in LDS
// with XOR swizzle (kg ^= row&7, both sides), read as 1 per-lane b128 per 4 k.
// FMA k-order + f64 64-k chunking identical to R6 -> bit-identical output.
__global__ __launch_bounds__(256)
void k1_proj(const float* __restrict__ x,
             const float* __restrict__ Wv, const float* __restrict__ bv,
             const float* __restrict__ Wk, const float* __restrict__ bk,
             const float* __restrict__ Wa, const float* __restrict__ ba,
             float* __restrict__ vOut, float* __restrict__ kOut,
             float* __restrict__ aOut)
{
    __shared__ float sX[64 * 64];                 // 16 KB, swizzled 16B groups
    const int tid  = threadIdx.x;
    const int lane = tid & 63;                    // row within block
    const int wq   = __builtin_amdgcn_readfirstlane(tid >> 6);   // wave id 0..3
    const int rb   = (blockIdx.x >> 2) * 64;      // 128 row-blocks x 64 rows
    const int cb   = ((blockIdx.x & 3) << 4) + (wq << 2);        // col base 0..60

    const float* pWv = Wv + (size_t)cb * IND;     // 4 rows each, wave-uniform
    const float* pWk = Wk + (size_t)cb * IND;
    const float* pWa = Wa + (size_t)cb * IND;

    double av[4] = {}, ak[4] = {}, aa[4] = {};

    for (int ko = 0; ko < IND; ko += 64) {
        __syncthreads();
        {   // stage x rows [rb, rb+64), k [ko, ko+64) with XOR-swizzled groups
            int r   = tid >> 2;                   // 0..63
            int kg0 = (tid & 3) << 2;             // kg start: 0,4,8,12
            const float* src = x + (size_t)(rb + r) * IND + ko + (kg0 << 2);
            #pragma unroll
            for (int j = 0; j < 4; ++j) {
                float4 v4 = *(const float4*)(src + (j << 2));
                int pk = (kg0 + j) ^ (r & 7);
                *(float4*)&sX[(r << 6) + (pk << 2)] = v4;
            }
        }
        __syncthreads();

        float fv[4] = {}, fk[4] = {}, fa[4] = {};
        #pragma unroll
        for (int kg = 0; kg < 16; ++kg) {
            float4 xv = *(const float4*)&sX[(lane << 6) + (((kg ^ (lane & 7))) << 2)];
            const int kk = ko + (kg << 2);
            float4 wv0 = *(const float4*)(pWv + 0 * IND + kk);   // uniform: s_load
            float4 wv1 = *(const float4*)(pWv + 1 * IND + kk);
            float4 wv2 = *(const float4*)(pWv + 2 * IND + kk);
            float4 wv3 = *(const float4*)(pWv + 3 * IND + kk);
            float4 wk0 = *(const float4*)(pWk + 0 * IND + kk);
            float4 wk1 = *(const float4*)(pWk + 1 * IND + kk);
            float4 wk2 = *(const float4*)(pWk + 2 * IND + kk);
            float4 wk3 = *(const float4*)(pWk + 3 * IND + kk);
            float4 wa0 = *(const float4*)(pWa + 0 * IND + kk);
            float4 wa1 = *(const float4*)(pWa + 1 * IND + kk);
            float4 wa2 = *(const float4*)(pWa + 2 * IND + kk);
            float4 wa3 = *(const float4*)(pWa + 3 * IND + kk);
            // k ascending within each accumulator (bit-identical to R6)
            fv[0]=fmaf(xv.x,wv0.x,fv[0]); fv[0]=fmaf(xv.y,wv0.y,fv[0]); fv[0]=fmaf(xv.z,wv0.z,fv[0]); fv[0]=fmaf(xv.w,wv0.w,fv[0]);
            fv[1]=fmaf(xv.x,wv1.x,fv[1]); fv[1]=fmaf(xv.y,wv1.y,fv[1]); fv[1]=fmaf(xv.z,wv1.z,fv[1]); fv[1]=fmaf(xv.w,wv1.w,fv[1]);
            fv[2]=fmaf(xv.x,wv2.x,fv[2]); fv[2]=fmaf(xv.y,wv2.y,fv[2]); fv[2]=fmaf(xv.z,wv2.z,fv[2]); fv[2]=fmaf(xv.w,wv2.w,fv[2]);
            fv[3]=fmaf(xv.x,wv3.x,fv[3]); fv[3]=fmaf(xv.y,wv3.y,fv[3]); fv[3]=fmaf(xv.z,wv3.z,fv[3]); fv[3]=fmaf(xv.w,wv3.w,fv[3]);
            fk[0]=fmaf(xv.x,wk0.x,fk[0]); fk[0]=fmaf(xv.y,wk0.y,fk[0]); fk[0]=fmaf(xv.z,wk0.z,fk[0]); fk[0]=fmaf(xv.w,wk0.w,fk[0]);
            fk[1]=fmaf(xv.x,wk1.x,fk[1]); fk[1]=fmaf(xv.y,wk1.y,fk[1]); fk[1]=fmaf(xv.z,wk1.z,fk[1]); fk[1]=fmaf(xv.w,wk1.w,fk[1]);
            fk[2]=fmaf(xv.x,wk2.x,fk[2]); fk[2]=fmaf(xv.y,wk2.y,fk[2]); fk[2]=fmaf(xv.z,wk2.z,fk[2]); fk[2]=fmaf(xv.w,wk2.w,fk[2]);
            fk[3]=fmaf(xv.x,wk3.x,fk[3]); fk[3]=fmaf(xv.y,wk3.y,fk[3]); fk[3]=fmaf(xv.z,wk3.z,fk[3]); fk[3]=fmaf(xv.w,wk3.w,fk[3]);
            fa[0]=fmaf(xv.x,wa0.x,fa[0]); fa[0]=fmaf(xv.y,wa0.y,fa[0]); fa[0]=fmaf(xv.z,wa0.z,fa[0]); fa[0]=fmaf(xv.w,wa0.w,fa[0]);
            fa[1]=fmaf(xv.x,wa1.x,fa[1]); fa[1]=fmaf(xv.y,wa1.y,fa[1]); fa[1]=fmaf(xv.z,wa1.z,fa[1]); fa[1]=fmaf(xv.w,wa1.w,fa[1]);
            fa[2]=fmaf(xv.x,wa2.x,fa[2]); fa[2]=fmaf(xv.y,wa2.y,fa[2]); fa[2]=fmaf(xv.z,wa2.z,fa[2]); fa[2]=fmaf(xv.w,wa2.w,fa[2]);
            fa[3]=fmaf(xv.x,wa3.x,fa[3]); fa[3]=fmaf(xv.y,wa3.y,fa[3]); fa[3]=fmaf(xv.z,wa3.z,fa[3]); fa[3]=fmaf(xv.w,wa3.w,fa[3]);
        }
        #pragma unroll
        for (int c = 0; c < 4; ++c) { av[c] += fv[c]; ak[c] += fk[c]; aa[c] += fa[c]; }
    }

    const size_t row = (size_t)rb + lane;
    float4 vo, ko4, ao;
    vo.x  = (float)(av[0] + (double)bv[cb+0]); vo.y  = (float)(av[1] + (double)bv[cb+1]);
    vo.z  = (float)(av[2] + (double)bv[cb+2]); vo.w  = (float)(av[3] + (double)bv[cb+3]);
    ko4.x = (float)(ak[0] + (double)bk[cb+0]); ko4.y = (float)(ak[1] + (double)bk[cb+1]);
    ko4.z = (float)(ak[2] + (double)bk[cb+2]); ko4.w = (float)(ak[3] + (double)bk[cb+3]);
    ao.x = (float)(1.0 / (1.0 + exp(-(aa[0] + (double)ba[cb+0]))));
    ao.y = (float)(1.0 / (1.0 + exp(-(aa[1] + (double)ba[cb+1]))));
    ao.z = (float)(1.0 / (1.0 + exp(-(aa[2] + (double)ba[cb+2]))));
    ao.w = (float)(1.0 / (1.0 + exp(-(aa[3] + (double)ba[cb+3]))));
    *(float4*)&vOut[row * 64 + cb] = vo;
    *(float4*)&kOut[row * 64 + cb] = ko4;
    *(float4*)&aOut[row * 64 + cb] = ao;
}

// ---------------- K2a: per-chunk alpha products (R6 exact) ---------------------
__global__ __launch_bounds__(256)
void k2a_chunkprod(const float* __restrict__ alpha, double* __restrict__ cpA)
{
    int gt = blockIdx.x * 256 + threadIdx.x;      // 16384 = 32 chunks * 512 chains
    int ch = gt >> 9, chain = gt & 511;
    double p = 1.0;
    int base = (ch * CHL) * 512 + chain;
    #pragma unroll
    for (int i = 0; i < CHL; ++i) p *= (double)alpha[base + i * 512];
    cpA[gt] = p;
}

// ---------------- K2b: exclusive prefix product, register-staged (R6 exact) ----
__global__ __launch_bounds__(512)
void k2b_prefix(double* __restrict__ cpA)
{
    int chain = threadIdx.x;                      // 512 threads, 1 block
    double vals[NCH];
    #pragma unroll
    for (int ch = 0; ch < NCH; ++ch) vals[ch] = cpA[ch * 512 + chain];
    double run = 1.0;
    #pragma unroll
    for (int ch = 0; ch < NCH; ++ch) {
        cpA[ch * 512 + chain] = run;
        run *= vals[ch];
    }
}

// ---------------- K3: per-chunk partial C sums (R6 exact) ----------------------
__global__ __launch_bounds__(256)
void k3_csum(const float* __restrict__ vIn, const float* __restrict__ kIn,
             const float* __restrict__ alpha, const double* __restrict__ cpA,
             double* __restrict__ Csum)
{
    __shared__ double sV[CHL * 64];               // 16 KB
    const int tid = threadIdx.x;
    const int ch = blockIdx.x >> 3;
    const int b  = blockIdx.x & 7;
    #pragma unroll
    for (int q = 0; q < 8; ++q) {
        int idx = q * 256 + tid;
        int ti = idx >> 6, d = idx & 63;
        sV[idx] = (double)vIn[(((ch * CHL + ti) * BB) + b) * 64 + d];
    }
    __syncthreads();
    const int n = tid & 63;
    const int w = tid >> 6;
    double P = cpA[ch * 512 + b * 64 + n];
    double C[16];
    #pragma unroll
    for (int j = 0; j < 16; ++j) C[j] = 0.0;
    for (int i = 0; i < CHL; ++i) {
        int base = ((ch * CHL + i) * BB + b) * 64 + n;
        P *= (double)alpha[base];
        double invp = 1.0 / (P + EPSV);
        double kd = (double)kIn[base] * invp;
        const double* vrow = &sV[i * 64 + w * 16];
        #pragma unroll
        for (int j = 0; j < 16; ++j) C[j] = fma(vrow[j], kd, C[j]);
    }
    size_t cb = ((size_t)ch * 8 + b) * 4096 + (size_t)w * 1024 + n;
    #pragma unroll
    for (int j = 0; j < 16; ++j) Csum[cb + j * 64] = C[j];
}

// ---------------- K3b: exclusive prefix sum, register-staged (R6 exact) --------
__global__ __launch_bounds__(256)
void k3b_prefix(double* __restrict__ Csum)
{
    int s = blockIdx.x * 256 + threadIdx.x;       // 32768 chains
    int b = s >> 12, rest = s & 4095;
    double vals[NCH];
    #pragma unroll
    for (int ch = 0; ch < NCH; ++ch)
        vals[ch] = Csum[((size_t)ch * 8 + b) * 4096 + rest];
    double run = 0.0;
    #pragma unroll
    for (int ch = 0; ch < NCH; ++ch) {
        Csum[((size_t)ch * 8 + b) * 4096 + rest] = run;
        run += vals[ch];
    }
}

// ---------------- K4: main scan (R6 exact) -------------------------------------
__global__ __launch_bounds__(256)
void k4_scan(const float* __restrict__ vIn, const float* __restrict__ kIn,
             const float* __restrict__ alpha, const double* __restrict__ cpA,
             const double* __restrict__ Csum, float* __restrict__ outp)
{
    __shared__ double sV[CHL * 64];
    const int tid = threadIdx.x;
    const int ch = blockIdx.x >> 3;
    const int b  = blockIdx.x & 7;
    #pragma unroll
    for (int q = 0; q < 8; ++q) {
        int idx = q * 256 + tid;
        int ti = idx >> 6, d = idx & 63;
        sV[idx] = (double)vIn[(((ch * CHL + ti) * BB) + b) * 64 + d];
    }
    __syncthreads();
    const int n = tid & 63;
    const int w = tid >> 6;
    double P = cpA[ch * 512 + b * 64 + n];
    size_t cb = ((size_t)ch * 8 + b) * 4096 + (size_t)w * 1024 + n;
    double C[16];
    #pragma unroll
    for (int j = 0; j < 16; ++j) C[j] = Csum[cb + j * 64];

    float* spk = outp;
    float* mem = outp + OUTHALF;
    for (int i = 0; i < CHL; ++i) {
        int t = ch * CHL + i;
        int base = (t * BB + b) * 64 + n;
        P *= (double)alpha[base];
        double invp = 1.0 / (P + EPSV);
        double kd = (double)kIn[base] * invp;
        const double* vrow = &sV[i * 64 + w * 16];
        size_t ob = ((size_t)t * BB + b) * 4096 + (size_t)w * 1024 + n;
        #pragma unroll
        for (int j = 0; j < 16; ++j) {
            C[j] = fma(vrow[j], kd, C[j]);
            double S = P * C[j];
            mem[ob + j * 64] = (float)S;
            spk[ob + j * 64] = (S > 1.0) ? 1.0f : 0.0f;
        }
    }
}

// ---------------- launch -------------------------------------------------------
extern "C" void kernel_launch(void* const* d_in, const int* in_sizes, int n_in,
                              void* d_out, int out_size, void* d_ws, size_t ws_size,
                              hipStream_t stream)
{
    const float* x  = (const float*)d_in[0];
    const float* Wv = (const float*)d_in[1];
    const float* bv = (const float*)d_in[2];
    const float* Wk = (const float*)d_in[3];
    const float* bk = (const float*)d_in[4];
    const float* Wa = (const float*)d_in[5];
    const float* ba = (const float*)d_in[6];
    float* out = (float*)d_out;

    char* ws = (char*)d_ws;
    float*  v     = (float*)(ws);                                   // 2 MB
    float*  kk    = (float*)(ws + (2u << 20));                      // 2 MB
    float*  alpha = (float*)(ws + (4u << 20));                      // 2 MB
    double* cpA   = (double*)(ws + (6u << 20));                     // 128 KB
    double* Csum  = (double*)(ws + (7u << 20));                     // 8 MB

    hipLaunchKernelGGL(k1_proj,       dim3(512), dim3(256), 0, stream,
                       x, Wv, bv, Wk, bk, Wa, ba, v, kk, alpha);
    hipLaunchKernelGGL(k2a_chunkprod, dim3(64),  dim3(256), 0, stream, alpha, cpA);
    hipLaunchKernelGGL(k2b_prefix,    dim3(1),   dim3(512), 0, stream, cpA);
    hipLaunchKernelGGL(k3_csum,       dim3(256), dim3(256), 0, stream,
                       v, kk, alpha, cpA, Csum);
    hipLaunchKernelGGL(k3b_prefix,    dim3(128), dim3(256), 0, stream, Csum);
    hipLaunchKernelGGL(k4_scan,       dim3(256), dim3(256), 0, stream,
                       v, kk, alpha, cpA, Csum, out);
}